// Round 1
// baseline (383.691 us; speedup 1.0000x reference)
//
#include <hip/hip_runtime.h>

#define NN 20000
#define EE 320000
#define BB 64
#define DD 256
#define DEPTH 3
#define NT (NN + BB)   // h rows + hs rows appended (NT = 20064 = 32*627 = 8*2508 = 16*1254)

typedef __attribute__((ext_vector_type(8))) short short8;
typedef __attribute__((ext_vector_type(4))) float floatx4;

// ---------------------------------------------------------------- bf16 split helpers
__device__ __forceinline__ short f2bf(float x) {
  union { float f; unsigned u; } v; v.f = x;
  unsigned r = v.u + 0x7fffu + ((v.u >> 16) & 1u);  // RNE
  return (short)(r >> 16);
}
__device__ __forceinline__ float bf2f(short s) {
  union { unsigned u; float f; } v; v.u = ((unsigned)(unsigned short)s) << 16;
  return v.f;
}

// ---------------------------------------------------------------- fragment-order split store
// A-fragment layout (round-18): Af[(((row>>4)*8 + kc)*2 + plane)*512 + (kg*16 + (row&15))*8 + kel]
// (shorts; plane 0 = hi, 1 = lo; kc = k>>5, kg = (k>>3)&3, kel = k&7). A wave's 16x32
// fragment (lane = kg*16+m16 -> 8 elems) is then ONE contiguous coalesced 1KB load,
// exactly like the Bf layout from round-15/16. Producers write 8B-aligned uint2 pairs.
// Numerically identical to the old per-kUpdM LDS split: same f32 -> same hi/lo.
__device__ __forceinline__ void storeFrag8(short* __restrict__ P, int row, int colB,
                                           float x, float y, float z, float wv) {
  short h0 = f2bf(x), h1 = f2bf(y), h2 = f2bf(z), h3 = f2bf(wv);
  short l0 = f2bf(x - bf2f(h0)), l1 = f2bf(y - bf2f(h1));
  short l2 = f2bf(z - bf2f(h2)), l3 = f2bf(wv - bf2f(h3));
  uint2 H, L;
  H.x = (unsigned)(unsigned short)h0 | ((unsigned)(unsigned short)h1 << 16);
  H.y = (unsigned)(unsigned short)h2 | ((unsigned)(unsigned short)h3 << 16);
  L.x = (unsigned)(unsigned short)l0 | ((unsigned)(unsigned short)l1 << 16);
  L.y = (unsigned)(unsigned short)l2 | ((unsigned)(unsigned short)l3 << 16);
  int kc  = colB >> 5;
  int kg  = (colB >> 3) & 3;
  int kel = colB & 7;                       // 0 or 4 (colB is a multiple of 4)
  size_t u = ((size_t)((row >> 4) * 8 + kc) * 2) * 512 + (size_t)(kg * 16 + (row & 15)) * 8 + kel;
  *(uint2*)(P + u) = H;
  *(uint2*)(P + u + 512) = L;
}

// ---------------------------------------------------------------- reductions
__device__ __forceinline__ float blockSum256(float v, float* tmp) {
  #pragma unroll
  for (int o = 32; o > 0; o >>= 1) v += __shfl_down(v, o, 64);
  if ((threadIdx.x & 63) == 0) tmp[threadIdx.x >> 6] = v;
  __syncthreads();
  float r = tmp[0] + tmp[1] + tmp[2] + tmp[3];
  __syncthreads();
  return r;
}

// ---------------------------------------------------------------- kPre: rank atomics + kM + encode
// SINGLE atomic pass over edges: rank[e] = atomicAdd(curn[dst],1) (round-13: -22us).
// B matrix written in MFMA-FRAGMENT ORDER (round-15/16). Encode now ALSO emits the
// split-bf16 A-fragments (round-18) alongside the f32 h that kAgg gathers.
#define NCB ((EE + 255) / 256)   // 1250
__global__ __launch_bounds__(256) void kPre(const float* __restrict__ X,
                                            const float* __restrict__ Xs,
                                            const float* __restrict__ W1,
                                            float* __restrict__ h,
                                            short* __restrict__ Af,
                                            const int* __restrict__ dst,
                                            const int* __restrict__ bassign,
                                            int* curn, int* curb,
                                            int* __restrict__ rank,
                                            int* __restrict__ rankB,
                                            const float* __restrict__ W2,
                                            const float* __restrict__ W3,
                                            const float* __restrict__ linW,
                                            short* __restrict__ Bf) {
  __shared__ int hb[64], rs[64], hc[64];
  int bid = blockIdx.x, j = threadIdx.x;
  if (bid < NCB) {
    if (j < 64) { hb[j] = 0; hc[j] = 0; }
    __syncthreads();
    int t = bid * 256 + j;
    int b = -1;
    if (t < NN) { b = bassign[t]; atomicAdd(&hb[b], 1); }
    __syncthreads();
    if (j < 64 && hb[j] > 0) rs[j] = atomicAdd(&curb[j], hb[j]);
    __syncthreads();
    if (t < NN) rankB[t] = rs[b] + atomicAdd(&hc[b], 1);
    if (t < EE) rank[t] = atomicAdd(&curn[dst[t]], 1);
  } else if (bid < NCB + 512) {
    // ---- M2 = W2 @ linW[0:256,:], M3 = W3 @ linW[256:512,:], fragment-order split
    int i = (bid - NCB) & 255;
    bool second = (bid - NCB) >= 256;
    const float* W = second ? W3 : W2;
    const float* L = linW + (second ? DD * DD : 0);
    float acc = 0.f;
    #pragma unroll 4
    for (int k = 0; k < DD; k++) acc = fmaf(W[i * DD + k], L[k * DD + j], acc);
    short hi = f2bf(acc);
    short lo = f2bf(acc - bf2f(hi));
    int kk = second ? (DD + i) : i;          // k index in B' (0..511)
    int kc = kk >> 5, kg = (kk >> 3) & 3, kel = kk & 7;
    int n16 = j >> 4, m16 = j & 15;
    size_t idx = ((size_t)(kc * 16 + n16) * 2) * 512 + (kg * 16 + m16) * 8 + kel;
    Bf[idx] = hi;
    Bf[idx + 512] = lo;
  } else {
    int r = (bid - NCB - 512) * 4 + (j >> 6);     // wave-per-row
    int lane = j & 63, c0 = lane * 4;
    const float* x = (r < NN) ? (X + (size_t)r * 2) : (Xs + (size_t)(r - NN) * 2);
    float x0 = x[0], x1 = x[1];
    float4 wa = *(const float4*)(W1 + c0);
    float4 wb = *(const float4*)(W1 + DD + c0);
    float4 v;
    v.x = fmaxf(fmaf(x0, wa.x, x1 * wb.x), 0.f);
    v.y = fmaxf(fmaf(x0, wa.y, x1 * wb.y), 0.f);
    v.z = fmaxf(fmaf(x0, wa.z, x1 * wb.z), 0.f);
    v.w = fmaxf(fmaf(x0, wa.w, x1 * wb.w), 0.f);
    float ss = v.x * v.x + v.y * v.y + v.z * v.z + v.w * v.w;
    #pragma unroll
    for (int o = 1; o < 64; o <<= 1) ss += __shfl_xor(ss, o, 64);
    float inv = 1.f / fmaxf(sqrtf(ss), 1e-12f);
    v.x *= inv; v.y *= inv; v.z *= inv; v.w *= inv;
    *(float4*)(h + (size_t)r * DD + c0) = v;
    storeFrag8(Af, r, c0, v.x, v.y, v.z, v.w);
  }
}

// ---------------------------------------------------------------- CSR scan (counts live in curn/curb)
__global__ __launch_bounds__(1024) void kScan(const int* __restrict__ curn,
                                              int* offn,
                                              const int* __restrict__ curb,
                                              int* offb) {
  __shared__ int sums[1024];
  int t = threadIdx.x;
  const int CH = 20;  // 1024*20 = 20480 >= NN
  int base = t * CH;
  int local[CH];
  int s = 0;
  #pragma unroll
  for (int i = 0; i < CH; i++) {
    int idx = base + i;
    int v = (idx < NN) ? curn[idx] : 0;
    local[i] = s;
    s += v;
  }
  sums[t] = s;
  __syncthreads();
  for (int o = 1; o < 1024; o <<= 1) {
    int x = (t >= o) ? sums[t - o] : 0;
    __syncthreads();
    sums[t] += x;
    __syncthreads();
  }
  int excl = sums[t] - s;
  #pragma unroll
  for (int i = 0; i < CH; i++) {
    int idx = base + i;
    if (idx < NN) offn[idx] = excl + local[i];
  }
  if (t == 1023) offn[NN] = sums[1023];
  // batch offsets: 64-lane shuffle scan (first wave)
  if (t < 64) {
    int v = curb[t];
    int incl = v;
    #pragma unroll
    for (int o = 1; o < 64; o <<= 1) {
      int x = __shfl_up(incl, o, 64);
      if (t >= o) incl += x;
    }
    offb[t] = incl - v;
    if (t == 63) offb[BB] = incl;
  }
}

// ---------------------------------------------------------------- kPlace: rank -> position, no atomics
__global__ __launch_bounds__(256) void kPlace(const int* __restrict__ src,
                                              const int* __restrict__ dst,
                                              const float* __restrict__ w,
                                              const int* __restrict__ bassign,
                                              const int* __restrict__ offn,
                                              const int* __restrict__ offb,
                                              const int* __restrict__ rank,
                                              const int* __restrict__ rankB,
                                              long long* sedge, int* snode) {
  int t = blockIdx.x * 256 + threadIdx.x;
  if (t < EE) {
    unsigned long long e = (unsigned long long)(unsigned)src[t]
                         | ((unsigned long long)(unsigned)__float_as_int(w[t]) << 32);
    sedge[offn[dst[t]] + rank[t]] = (long long)e;
  }
  if (t < NN) snode[offb[bassign[t]] + rankB[t]] = t;
}

// ---------------------------------------------------------------- aggregation (XCD-sliced, 8 waves = 8 nodes)
// STRUCTURAL FLOOR (declared): 2.56M distinct 128B gather lines/dispatch = 10K/CU;
// at ~350cyc L2-hit-under-load and ~32 outstanding L1 misses/CU -> 1 line/10.9cyc
// -> 45.5us model vs ~47 measured. Rounds 7/9/12 structures all converge here.
// round-18: epilogue now writes split-bf16 fragments (Avf) instead of f32 hnv --
// kUpdM consumes these directly; the f32 hnv buffer is gone. Same f32 acc values
// go through the same split -> bit-identical downstream math.
#define ECAP 1024   // staged edges per chunk (8 KB)
__global__ __launch_bounds__(512) void kAgg(const float* __restrict__ h,
                                            const int* __restrict__ offn,
                                            const long long* __restrict__ sedge,
                                            const int* __restrict__ offb,
                                            const int* __restrict__ snode,
                                            short* __restrict__ Avf) {
  __shared__ __align__(16) long long Led[ECAP];
  int bid = blockIdx.x;
  int slice = bid & 7, group = bid >> 3;      // group 0..2507
  int t = threadIdx.x;
  int w = t >> 6, lane = t & 63;
  int eg = lane >> 3;          // edge group 0..7
  int pc = lane & 7;           // float4 piece 0..7
  int colB = slice * 32 + pc * 4;
  float4 acc = make_float4(0.f, 0.f, 0.f, 0.f);

  if (group < 8) {
    // ---- batch rows: nodes 0..63 (8 per block), snode index list (weight 1)
    int b0 = group * 8;
    int s0 = offb[b0], e0 = offb[b0 + 8];
    int sW = offb[b0 + w], eW = offb[b0 + w + 1];
    int* Li = (int*)Led;
    for (int base = s0; base < e0; base += 2 * ECAP) {
      int cnt = min(e0 - base, 2 * ECAP);
      __syncthreads();
      for (int i = t; i < cnt; i += 512) Li[i] = snode[base + i];
      __syncthreads();
      int lo = max(sW, base), hi = min(eW, base + cnt);
      for (int i = lo; i < hi; i += 16) {
        int i0 = i + eg, i1 = i + 8 + eg;
        int n0 = Li[min(i0, hi - 1) - base];
        int n1 = Li[min(i1, hi - 1) - base];
        float w0 = (i0 < hi) ? 1.f : 0.f;
        float w1 = (i1 < hi) ? 1.f : 0.f;
        float4 v0 = *(const float4*)(h + (size_t)n0 * DD + colB);
        float4 v1 = *(const float4*)(h + (size_t)n1 * DD + colB);
        acc.x = fmaf(w0, v0.x, fmaf(w1, v1.x, acc.x));
        acc.y = fmaf(w0, v0.y, fmaf(w1, v1.y, acc.y));
        acc.z = fmaf(w0, v0.z, fmaf(w1, v1.z, acc.z));
        acc.w = fmaf(w0, v0.w, fmaf(w1, v1.w, acc.w));
      }
    }
    #pragma unroll
    for (int o = 8; o < 64; o <<= 1) {
      acc.x += __shfl_xor(acc.x, o, 64);
      acc.y += __shfl_xor(acc.y, o, 64);
      acc.z += __shfl_xor(acc.z, o, 64);
      acc.w += __shfl_xor(acc.w, o, 64);
    }
    if (eg == 0) storeFrag8(Avf, NN + b0 + w, colB, acc.x, acc.y, acc.z, acc.w);
  } else {
    // ---- edge nodes, 8 per block
    int first = (group - 8) * 8;
    int s0 = offn[first], e0 = offn[first + 8];
    int sW = offn[first + w], eW = offn[first + w + 1];
    for (int base = s0; base < e0; base += ECAP) {
      int cnt = min(e0 - base, ECAP);
      __syncthreads();
      for (int i = t; i < cnt; i += 512) Led[i] = sedge[base + i];
      __syncthreads();
      int lo = max(sW, base), hi = min(eW, base + cnt);
      for (int i = lo; i < hi; i += 16) {
        int i0 = i + eg, i1 = i + 8 + eg;
        long long e0v = Led[min(i0, hi - 1) - base];
        long long e1v = Led[min(i1, hi - 1) - base];
        float w0 = (i0 < hi) ? __int_as_float((int)(e0v >> 32)) : 0.f;
        float w1 = (i1 < hi) ? __int_as_float((int)(e1v >> 32)) : 0.f;
        unsigned r0 = (unsigned)(e0v & 0xffffffffLL);
        unsigned r1 = (unsigned)(e1v & 0xffffffffLL);
        float4 v0 = *(const float4*)(h + (size_t)r0 * DD + colB);
        float4 v1 = *(const float4*)(h + (size_t)r1 * DD + colB);
        acc.x = fmaf(w0, v0.x, fmaf(w1, v1.x, acc.x));
        acc.y = fmaf(w0, v0.y, fmaf(w1, v1.y, acc.y));
        acc.z = fmaf(w0, v0.z, fmaf(w1, v1.z, acc.z));
        acc.w = fmaf(w0, v0.w, fmaf(w1, v1.w, acc.w));
      }
    }
    #pragma unroll
    for (int o = 8; o < 64; o <<= 1) {
      acc.x += __shfl_xor(acc.x, o, 64);
      acc.y += __shfl_xor(acc.y, o, 64);
      acc.z += __shfl_xor(acc.z, o, 64);
      acc.w += __shfl_xor(acc.w, o, 64);
    }
    if (eg == 0) storeFrag8(Avf, first + w, colB, acc.x, acc.y, acc.z, acc.w);
  }
}

// ---------------------------------------------------------------- MFMA dual-GEMM + fused l2norm
// round-18: BARRIER-FREE main loop. A arrives pre-split in fragment order (Af from
// kPre/kUpdM epilogues, Avf from kAgg) -- per kc each wave issues 8 perfectly
// coalesced 1KB loads (4 A-frag, wave-uniform -> L1-hit for 7/8 waves; 4 B-frag
// from L2-resident Bf) + 12 MFMAs. No LDS staging, no per-kc conversion, no
// __syncthreads until the epilogue. Floor: B L2 re-read 627x512KB = 320MB ~ 9.3us,
// HBM writes 40MB ~ 6.4us, MFMA ~1.9us.
// Af is updated IN PLACE: a block reads only its own 32 rows' fragments (all kc)
// before its epilogue rewrites those same rows. Epilogue bounces the normalized
// f32 tile through LDS Ct[32][260] (pad 260: stride%32=4 -> 2-way write aliasing
// = free; 260*4B = 65*16B -> b128 row reads stay 16B-aligned) to emit both the f32
// h (for kAgg gathers / kDec) and the fragment-order split planes coalesced.
#define TRU 32
__global__ __launch_bounds__(512) void kUpdM(short* __restrict__ Af,
                                             const short* __restrict__ Avf,
                                             const short* __restrict__ Bf,
                                             const float* __restrict__ lb,
                                             float* __restrict__ out) {
  __shared__ float ssq[8][TRU];
  __shared__ __align__(16) float Ct[TRU][260];
  const int t = threadIdx.x;
  const int rb = blockIdx.x * TRU;
  const int wid = t >> 6;          // 0..7
  const int lane = t & 63;
  const int wc = wid * 32;         // wave col offset (8 waves cover 256 cols)
  const int m16 = lane & 15;
  const int kg = lane >> 4;        // 0..3
  const int r16b = rb >> 4;

  floatx4 acc[2][2];
  #pragma unroll
  for (int ct = 0; ct < 2; ct++) {
    float b = lb[wc + ct * 16 + m16];
    #pragma unroll
    for (int rt = 0; rt < 2; rt++) acc[rt][ct] = (floatx4){b, b, b, b};
  }

  for (int half = 0; half < 2; ++half) {
    const short* Ab = half ? Avf : (const short*)Af;
    #pragma unroll 2
    for (int kcl = 0; kcl < 8; ++kcl) {
      const int kc = half * 8 + kcl;
      short8 ah[2], al_[2];
      #pragma unroll
      for (int rt = 0; rt < 2; rt++) {
        const short* ap = Ab + ((size_t)((r16b + rt) * 8 + kcl) * 2) * 512 + lane * 8;
        ah[rt]  = *(const short8*)ap;
        al_[rt] = *(const short8*)(ap + 512);
      }
      #pragma unroll
      for (int ct = 0; ct < 2; ct++) {
        const short* bp = Bf + ((size_t)(kc * 16 + wid * 2 + ct) * 2) * 512 + lane * 8;
        short8 bh = *(const short8*)bp;
        short8 bl = *(const short8*)(bp + 512);
        #pragma unroll
        for (int rt = 0; rt < 2; rt++) {
          acc[rt][ct] = __builtin_amdgcn_mfma_f32_16x16x32_bf16(ah[rt], bh, acc[rt][ct], 0, 0, 0);
          acc[rt][ct] = __builtin_amdgcn_mfma_f32_16x16x32_bf16(ah[rt], bl, acc[rt][ct], 0, 0, 0);
          acc[rt][ct] = __builtin_amdgcn_mfma_f32_16x16x32_bf16(al_[rt], bh, acc[rt][ct], 0, 0, 0);
        }
      }
    }
  }

  // ---- epilogue: relu + row l2norm (C/D: col=lane&15, row=(lane>>4)*4+reg)
  float p[2][4];
  #pragma unroll
  for (int rt = 0; rt < 2; rt++)
    #pragma unroll
    for (int reg = 0; reg < 4; reg++) {
      float s = 0.f;
      #pragma unroll
      for (int ct = 0; ct < 2; ct++) {
        float x = fmaxf(acc[rt][ct][reg], 0.f);
        s = fmaf(x, x, s);
      }
      p[rt][reg] = s;
    }
  #pragma unroll
  for (int o = 1; o < 16; o <<= 1)
    #pragma unroll
    for (int rt = 0; rt < 2; rt++)
      #pragma unroll
      for (int reg = 0; reg < 4; reg++)
        p[rt][reg] += __shfl_xor(p[rt][reg], o, 64);
  if (m16 == 0) {
    #pragma unroll
    for (int rt = 0; rt < 2; rt++)
      #pragma unroll
      for (int reg = 0; reg < 4; reg++)
        ssq[wid][rt * 16 + kg * 4 + reg] = p[rt][reg];
  }
  __syncthreads();
  #pragma unroll
  for (int rt = 0; rt < 2; rt++) {
    #pragma unroll
    for (int reg = 0; reg < 4; reg++) {
      int row = rt * 16 + kg * 4 + reg;
      float ss = 0.f;
      #pragma unroll
      for (int ww = 0; ww < 8; ww++) ss += ssq[ww][row];
      float inv = 1.f / fmaxf(sqrtf(ss), 1e-12f);
      #pragma unroll
      for (int ct = 0; ct < 2; ct++) {
        int col = wc + ct * 16 + m16;
        float v = fmaxf(acc[rt][ct][reg], 0.f) * inv;
        out[(size_t)(rb + row) * DD + col] = v;
        Ct[row][col] = v;
      }
    }
  }
  __syncthreads();
  // ---- fragment-order split write-back (in-place Af), coalesced 16B stores
  const int fl = lane;                 // lane-in-fragment
  const int fk = wid;                  // kc 0..7
  #pragma unroll
  for (int r16o = 0; r16o < 2; ++r16o) {
    int row = r16o * 16 + (fl & 15);
    int k0 = fk * 32 + (fl >> 4) * 8;
    float4 xa = *(const float4*)&Ct[row][k0];
    float4 xb = *(const float4*)&Ct[row][k0 + 4];
    short8 H, L;
    H[0] = f2bf(xa.x); H[1] = f2bf(xa.y); H[2] = f2bf(xa.z); H[3] = f2bf(xa.w);
    H[4] = f2bf(xb.x); H[5] = f2bf(xb.y); H[6] = f2bf(xb.z); H[7] = f2bf(xb.w);
    L[0] = f2bf(xa.x - bf2f(H[0])); L[1] = f2bf(xa.y - bf2f(H[1]));
    L[2] = f2bf(xa.z - bf2f(H[2])); L[3] = f2bf(xa.w - bf2f(H[3]));
    L[4] = f2bf(xb.x - bf2f(H[4])); L[5] = f2bf(xb.y - bf2f(H[5]));
    L[6] = f2bf(xb.z - bf2f(H[6])); L[7] = f2bf(xb.w - bf2f(H[7]));
    size_t u = ((size_t)((r16b + r16o) * 8 + fk) * 2) * 512 + (size_t)fl * 8;
    *(short8*)(Af + u) = H;
    *(short8*)(Af + u + 512) = L;
  }
}

// ---------------------------------------------------------------- decode
__global__ __launch_bounds__(256) void kDec(const float* __restrict__ h,
                                            const int* __restrict__ aidx,
                                            const float* __restrict__ W4,
                                            const float* __restrict__ W5,
                                            float* __restrict__ Q) {
  __shared__ float tmp[4];
  int b = blockIdx.x, j = threadIdx.x;
  float s = blockSum256(h[(size_t)(NN + b) * DD + j] * W4[j], tmp);
  int a = aidx[b];
  float za = h[(size_t)a * DD + j];
  float q = blockSum256(fmaxf(za * s, 0.f) * W5[j], tmp);
  if (j == 0) Q[b] = q;
}

// ---------------------------------------------------------------- launcher
extern "C" void kernel_launch(void* const* d_in, const int* in_sizes, int n_in,
                              void* d_out, int out_size, void* d_ws, size_t ws_size,
                              hipStream_t stream) {
  (void)in_sizes; (void)n_in; (void)out_size; (void)ws_size;
  const int*   edge_src = (const int*)d_in[0];
  const int*   edge_dst = (const int*)d_in[1];
  const float* edge_w   = (const float*)d_in[2];
  const int*   bassign  = (const int*)d_in[3];
  const int*   aidx     = (const int*)d_in[4];
  const float* Xf       = (const float*)d_in[5];
  const float* Xs       = (const float*)d_in[6];
  const float* W1       = (const float*)d_in[7];
  const float* W2       = (const float*)d_in[8];
  const float* W3       = (const float*)d_in[9];
  const float* linW     = (const float*)d_in[10];
  const float* linB     = (const float*)d_in[11];
  const float* W4       = (const float*)d_in[12];
  const float* W5       = (const float*)d_in[13];
  float* Q = (float*)d_out;

  char* base = (char*)d_ws;
  const size_t NB = (size_t)NT * DD * 4;   // 20.5 MB; also == split-fragment plane-pair bytes
  float* h    = (float*)(base);            // f32 h, in-place across depths (kAgg/kDec)
  short* Af   = (short*)(base + NB);       // split A-fragments, in-place across depths
  short* Avf  = (short*)(base + 2 * NB);   // split hnv-fragments (rewritten each depth)
  size_t o = 3 * NB;
  short* Bf   = (short*)(base + o); o += (size_t)DD * 512 * 2 * 2;  // 512 KB, fragment order
  long long* sedge = (long long*)(base + o); o += (size_t)EE * 8;
  int*   snode= (int*)(base + o);   o += (size_t)NN * 4;
  int*   rank = (int*)(base + o);   o += (size_t)EE * 4;
  int*   rankB= (int*)(base + o);   o += (size_t)NN * 4;
  int*   offn = (int*)(base + o);   o += (size_t)(NN + 4) * 4;
  int*   offb = (int*)(base + o);   o += (size_t)(BB + 4) * 4;
  int*   curn = (int*)(base + o);   o += (size_t)NN * 4;
  int*   curb = (int*)(base + o);   o += (size_t)BB * 4;   // contiguous with curn

  hipMemsetAsync(curn, 0, (size_t)(NN + BB) * 4, stream);

  kPre<<<NCB + 512 + NT / 4, 256, 0, stream>>>(Xf, Xs, W1, h, Af,
                                               edge_dst, bassign, curn, curb,
                                               rank, rankB,
                                               W2, W3, linW, Bf);
  kScan<<<1, 1024, 0, stream>>>(curn, offn, curb, offb);
  kPlace<<<(EE + 255) / 256, 256, 0, stream>>>(edge_src, edge_dst, edge_w, bassign,
                                               offn, offb, rank, rankB, sedge, snode);
  for (int d = 0; d < DEPTH; d++) {
    kAgg<<<8 * (NT / 8), 512, 0, stream>>>(h, offn, sedge, offb, snode, Avf);
    kUpdM<<<NT / TRU, 512, 0, stream>>>(Af, Avf, Bf, linB, h);
  }
  kDec<<<BB, 256, 0, stream>>>(h, aidx, W4, W5, Q);
}

// Round 2
// 340.417 us; speedup vs baseline: 1.1271x; 1.1271x over previous
//
#include <hip/hip_runtime.h>

#define NN 20000
#define EE 320000
#define BB 64
#define DD 256
#define DEPTH 3
#define NT (NN + BB)   // h rows + hs rows appended (NT = 20064 = 16*1254 = 32*627 = 8*2508)

typedef __attribute__((ext_vector_type(8))) short short8;
typedef __attribute__((ext_vector_type(4))) float floatx4;

// ---------------------------------------------------------------- bf16 split helpers
__device__ __forceinline__ short f2bf(float x) {
  union { float f; unsigned u; } v; v.f = x;
  unsigned r = v.u + 0x7fffu + ((v.u >> 16) & 1u);  // RNE
  return (short)(r >> 16);
}
__device__ __forceinline__ float bf2f(short s) {
  union { unsigned u; float f; } v; v.u = ((unsigned)(unsigned short)s) << 16;
  return v.f;
}

// ---------------------------------------------------------------- fragment-order split store
// A-fragment layout: Af[(((row>>4)*8 + kc)*2 + plane)*512 + (kg*16 + (row&15))*8 + kel]
// (shorts; plane 0 = hi, 1 = lo; kc = k>>5, kg = (k>>3)&3, kel = k&7). A wave's 16x32
// fragment is ONE contiguous coalesced 1KB load in kUpdM.
// storeFragRow8: 8 consecutive cols (c0 % 8 == 0) of one row -> two 16B stores.
__device__ __forceinline__ void storeFragRow8(short* __restrict__ P, int row, int c0,
                                              const float* a) {
  short8 H, L;
  #pragma unroll
  for (int k = 0; k < 8; k++) {
    short hh = f2bf(a[k]);
    H[k] = hh;
    L[k] = f2bf(a[k] - bf2f(hh));
  }
  int kc = c0 >> 5, kg = (c0 >> 3) & 3;
  size_t u = ((size_t)((row >> 4) * 8 + kc) * 2) * 512 + (size_t)(kg * 16 + (row & 15)) * 8;
  *(short8*)(P + u) = H;
  *(short8*)(P + u + 512) = L;
}

// ---------------------------------------------------------------- reductions
__device__ __forceinline__ float blockSum256(float v, float* tmp) {
  #pragma unroll
  for (int o = 32; o > 0; o >>= 1) v += __shfl_down(v, o, 64);
  if ((threadIdx.x & 63) == 0) tmp[threadIdx.x >> 6] = v;
  __syncthreads();
  float r = tmp[0] + tmp[1] + tmp[2] + tmp[3];
  __syncthreads();
  return r;
}

// ---------------------------------------------------------------- kPre: rank atomics + kM + encode
// round-19: encode restructured to 16-rows-per-block so the Af fragment writes are
// COALESCED (a fragment interleaves 16 rows; a 16-row producer owns whole fragments;
// round-1's wave-per-row scatter cost 8B x 64-distinct-lines per wave -> 55.5MB
// WRITE_SIZE). f32 h is gone entirely: gathers/decode use bf16 hg (round-19).
#define NCB ((EE + 255) / 256)   // 1250
__global__ __launch_bounds__(256) void kPre(const float* __restrict__ X,
                                            const float* __restrict__ Xs,
                                            const float* __restrict__ W1,
                                            short* __restrict__ hg,
                                            short* __restrict__ Af,
                                            const int* __restrict__ dst,
                                            const int* __restrict__ bassign,
                                            int* curn, int* curb,
                                            int* __restrict__ rank,
                                            int* __restrict__ rankB,
                                            const float* __restrict__ W2,
                                            const float* __restrict__ W3,
                                            const float* __restrict__ linW,
                                            short* __restrict__ Bf) {
  __shared__ int hb[64], rs[64], hc[64];
  __shared__ __align__(16) short Hs[16][264];   // 264: stride 132 dwords %32 = 4 -> <=2-way
  __shared__ __align__(16) short Ls[16][264];
  int bid = blockIdx.x, j = threadIdx.x;
  if (bid < NCB) {
    if (j < 64) { hb[j] = 0; hc[j] = 0; }
    __syncthreads();
    int t = bid * 256 + j;
    int b = -1;
    if (t < NN) { b = bassign[t]; atomicAdd(&hb[b], 1); }
    __syncthreads();
    if (j < 64 && hb[j] > 0) rs[j] = atomicAdd(&curb[j], hb[j]);
    __syncthreads();
    if (t < NN) rankB[t] = rs[b] + atomicAdd(&hc[b], 1);
    if (t < EE) rank[t] = atomicAdd(&curn[dst[t]], 1);
  } else if (bid < NCB + 512) {
    // ---- M2 = W2 @ linW[0:256,:], M3 = W3 @ linW[256:512,:], fragment-order split
    int i = (bid - NCB) & 255;
    bool second = (bid - NCB) >= 256;
    const float* W = second ? W3 : W2;
    const float* L = linW + (second ? DD * DD : 0);
    float acc = 0.f;
    #pragma unroll 4
    for (int k = 0; k < DD; k++) acc = fmaf(W[i * DD + k], L[k * DD + j], acc);
    short hi = f2bf(acc);
    short lo = f2bf(acc - bf2f(hi));
    int kk = second ? (DD + i) : i;          // k index in B' (0..511)
    int kc = kk >> 5, kg = (kk >> 3) & 3, kel = kk & 7;
    int n16 = j >> 4, m16 = j & 15;
    size_t idx = ((size_t)(kc * 16 + n16) * 2) * 512 + (kg * 16 + m16) * 8 + kel;
    Bf[idx] = hi;
    Bf[idx + 512] = lo;
  } else {
    // ---- encode: 16 rows per block, 16 threads/row x 16 cols/thread
    int rg = bid - NCB - 512;        // row-group 0..1253
    int rl = j >> 4;                 // row-in-group 0..15 (16 lanes each, shfl<16 safe)
    int ci = j & 15;
    int r = rg * 16 + rl;
    int c0 = ci * 16;
    const float* x = (r < NN) ? (X + (size_t)r * 2) : (Xs + (size_t)(r - NN) * 2);
    float x0 = x[0], x1 = x[1];
    float v[16];
    float ss = 0.f;
    #pragma unroll
    for (int q = 0; q < 4; q++) {
      float4 wa = *(const float4*)(W1 + c0 + q * 4);
      float4 wb = *(const float4*)(W1 + DD + c0 + q * 4);
      float a0 = fmaxf(fmaf(x0, wa.x, x1 * wb.x), 0.f);
      float a1 = fmaxf(fmaf(x0, wa.y, x1 * wb.y), 0.f);
      float a2 = fmaxf(fmaf(x0, wa.z, x1 * wb.z), 0.f);
      float a3 = fmaxf(fmaf(x0, wa.w, x1 * wb.w), 0.f);
      v[q * 4 + 0] = a0; v[q * 4 + 1] = a1; v[q * 4 + 2] = a2; v[q * 4 + 3] = a3;
      ss = fmaf(a0, a0, ss); ss = fmaf(a1, a1, ss);
      ss = fmaf(a2, a2, ss); ss = fmaf(a3, a3, ss);
    }
    #pragma unroll
    for (int o = 1; o < 16; o <<= 1) ss += __shfl_xor(ss, o, 64);
    float inv = 1.f / fmaxf(sqrtf(ss), 1e-12f);
    short8 H0, H1, L0, L1;
    #pragma unroll
    for (int k = 0; k < 8; k++) {
      float s0 = v[k] * inv;
      float s1 = v[8 + k] * inv;
      short h0 = f2bf(s0), h1 = f2bf(s1);
      H0[k] = h0; H1[k] = h1;
      L0[k] = f2bf(s0 - bf2f(h0)); L1[k] = f2bf(s1 - bf2f(h1));
    }
    *(short8*)(hg + (size_t)r * DD + c0)     = H0;
    *(short8*)(hg + (size_t)r * DD + c0 + 8) = H1;
    *(short8*)&Hs[rl][c0] = H0;  *(short8*)&Hs[rl][c0 + 8] = H1;
    *(short8*)&Ls[rl][c0] = L0;  *(short8*)&Ls[rl][c0 + 8] = L1;
    __syncthreads();
    // ---- coalesced fragment write: thread j covers fragment kc=j>>5, positions j&31, +32
    int kc = j >> 5, p0 = j & 31;
    #pragma unroll
    for (int half = 0; half < 2; half++) {
      int p = p0 + half * 32;
      int prow = p & 15, kg = p >> 4;
      size_t ub = ((size_t)(rg * 8 + kc) * 2) * 512 + (size_t)p * 8;
      *(short8*)(Af + ub)       = *(const short8*)&Hs[prow][kc * 32 + kg * 8];
      *(short8*)(Af + ub + 512) = *(const short8*)&Ls[prow][kc * 32 + kg * 8];
    }
  }
}

// ---------------------------------------------------------------- CSR scan (counts live in curn/curb)
__global__ __launch_bounds__(1024) void kScan(const int* __restrict__ curn,
                                              int* offn,
                                              const int* __restrict__ curb,
                                              int* offb) {
  __shared__ int sums[1024];
  int t = threadIdx.x;
  const int CH = 20;  // 1024*20 = 20480 >= NN
  int base = t * CH;
  int local[CH];
  int s = 0;
  #pragma unroll
  for (int i = 0; i < CH; i++) {
    int idx = base + i;
    int v = (idx < NN) ? curn[idx] : 0;
    local[i] = s;
    s += v;
  }
  sums[t] = s;
  __syncthreads();
  for (int o = 1; o < 1024; o <<= 1) {
    int x = (t >= o) ? sums[t - o] : 0;
    __syncthreads();
    sums[t] += x;
    __syncthreads();
  }
  int excl = sums[t] - s;
  #pragma unroll
  for (int i = 0; i < CH; i++) {
    int idx = base + i;
    if (idx < NN) offn[idx] = excl + local[i];
  }
  if (t == 1023) offn[NN] = sums[1023];
  // batch offsets: 64-lane shuffle scan (first wave)
  if (t < 64) {
    int v = curb[t];
    int incl = v;
    #pragma unroll
    for (int o = 1; o < 64; o <<= 1) {
      int x = __shfl_up(incl, o, 64);
      if (t >= o) incl += x;
    }
    offb[t] = incl - v;
    if (t == 63) offb[BB] = incl;
  }
}

// ---------------------------------------------------------------- kPlace: rank -> position, no atomics
__global__ __launch_bounds__(256) void kPlace(const int* __restrict__ src,
                                              const int* __restrict__ dst,
                                              const float* __restrict__ w,
                                              const int* __restrict__ bassign,
                                              const int* __restrict__ offn,
                                              const int* __restrict__ offb,
                                              const int* __restrict__ rank,
                                              const int* __restrict__ rankB,
                                              long long* sedge, int* snode) {
  int t = blockIdx.x * 256 + threadIdx.x;
  if (t < EE) {
    unsigned long long e = (unsigned long long)(unsigned)src[t]
                         | ((unsigned long long)(unsigned)__float_as_int(w[t]) << 32);
    sedge[offn[dst[t]] + rank[t]] = (long long)e;
  }
  if (t < NN) snode[offb[bassign[t]] + rankB[t]] = t;
}

// ---------------------------------------------------------------- aggregation (XCD-sliced, 8 waves = 8 nodes)
// round-19: gather from bf16 hg (512B/row) instead of f32 h (1KB/row) -> distinct
// 128B gather lines HALVE (2.72M -> 1.36M/dispatch). 4 slices x 64 cols; one line
// per (edge,slice); slice = bid&3 so XCD x serves slice x&3 -> per-XCD working set
// NT*128B = 2.56MB, L2-resident. Added cvt VALU (~13us) stays under the ~23us
// latency floor. hnv sums bf16-rounded h (2^-9 rel) -- output-safe: s<0 => Q==0
// exactly for any magnitude perturbation (Za>=0 always).
#define ECAP 1024   // staged edges per chunk (8 KB)
__global__ __launch_bounds__(512) void kAgg(const short* __restrict__ hg,
                                            const int* __restrict__ offn,
                                            const long long* __restrict__ sedge,
                                            const int* __restrict__ offb,
                                            const int* __restrict__ snode,
                                            short* __restrict__ Avf) {
  __shared__ __align__(16) long long Led[ECAP];
  int bid = blockIdx.x;
  int slice = bid & 3, group = bid >> 2;      // group 0..2507
  int t = threadIdx.x;
  int w = t >> 6, lane = t & 63;
  int eg = lane >> 3;          // edge group 0..7
  int pc = lane & 7;           // 16B piece 0..7
  int colB = slice * 64 + pc * 8;             // 8 bf16 cols per lane
  float acc[8];
  #pragma unroll
  for (int jj = 0; jj < 8; jj++) acc[jj] = 0.f;

  if (group < 8) {
    // ---- batch rows: nodes 0..63 (8 per block), snode index list (weight 1)
    int b0 = group * 8;
    int s0 = offb[b0], e0 = offb[b0 + 8];
    int sW = offb[b0 + w], eW = offb[b0 + w + 1];
    int* Li = (int*)Led;
    for (int base = s0; base < e0; base += 2 * ECAP) {
      int cnt = min(e0 - base, 2 * ECAP);
      __syncthreads();
      for (int i = t; i < cnt; i += 512) Li[i] = snode[base + i];
      __syncthreads();
      int lo = max(sW, base), hi = min(eW, base + cnt);
      for (int i = lo; i < hi; i += 16) {
        int i0 = i + eg, i1 = i + 8 + eg;
        int n0 = Li[min(i0, hi - 1) - base];
        int n1 = Li[min(i1, hi - 1) - base];
        float w0 = (i0 < hi) ? 1.f : 0.f;
        float w1 = (i1 < hi) ? 1.f : 0.f;
        short8 a0 = *(const short8*)(hg + (size_t)n0 * DD + colB);
        short8 a1 = *(const short8*)(hg + (size_t)n1 * DD + colB);
        #pragma unroll
        for (int jj = 0; jj < 8; jj++)
          acc[jj] = fmaf(w1, bf2f(a1[jj]), fmaf(w0, bf2f(a0[jj]), acc[jj]));
      }
    }
    #pragma unroll
    for (int o = 8; o < 64; o <<= 1)
      #pragma unroll
      for (int jj = 0; jj < 8; jj++) acc[jj] += __shfl_xor(acc[jj], o, 64);
    if (eg == 0) storeFragRow8(Avf, NN + b0 + w, colB, acc);
  } else {
    // ---- edge nodes, 8 per block
    int first = (group - 8) * 8;
    int s0 = offn[first], e0 = offn[first + 8];
    int sW = offn[first + w], eW = offn[first + w + 1];
    for (int base = s0; base < e0; base += ECAP) {
      int cnt = min(e0 - base, ECAP);
      __syncthreads();
      for (int i = t; i < cnt; i += 512) Led[i] = sedge[base + i];
      __syncthreads();
      int lo = max(sW, base), hi = min(eW, base + cnt);
      for (int i = lo; i < hi; i += 16) {
        int i0 = i + eg, i1 = i + 8 + eg;
        long long e0v = Led[min(i0, hi - 1) - base];
        long long e1v = Led[min(i1, hi - 1) - base];
        float w0 = (i0 < hi) ? __int_as_float((int)(e0v >> 32)) : 0.f;
        float w1 = (i1 < hi) ? __int_as_float((int)(e1v >> 32)) : 0.f;
        unsigned r0 = (unsigned)(e0v & 0xffffffffLL);
        unsigned r1 = (unsigned)(e1v & 0xffffffffLL);
        short8 a0 = *(const short8*)(hg + (size_t)r0 * DD + colB);
        short8 a1 = *(const short8*)(hg + (size_t)r1 * DD + colB);
        #pragma unroll
        for (int jj = 0; jj < 8; jj++)
          acc[jj] = fmaf(w1, bf2f(a1[jj]), fmaf(w0, bf2f(a0[jj]), acc[jj]));
      }
    }
    #pragma unroll
    for (int o = 8; o < 64; o <<= 1)
      #pragma unroll
      for (int jj = 0; jj < 8; jj++) acc[jj] += __shfl_xor(acc[jj], o, 64);
    if (eg == 0) storeFragRow8(Avf, first + w, colB, acc);
  }
}

// ---------------------------------------------------------------- MFMA dual-GEMM + fused l2norm
// Barrier-free main loop: A pre-split in fragment order (Af from kPre/own epilogue,
// Avf from kAgg); per kc each wave: 8 coalesced 1KB loads (4 A-frag wave-uniform ->
// L1-hit for 7/8 waves; 4 B-frag from L2-resident Bf) + 12 MFMAs. Af updated
// IN PLACE (block reads only its own 32 rows before rewriting them). Epilogue
// bounces normalized f32 tile through LDS Ct and emits Af (hi+lo, contiguous 1KB
// per fragment) + bf16 hg (for kAgg gathers / kDec). No f32 h anymore.
#define TRU 32
__global__ __launch_bounds__(512) void kUpdM(short* __restrict__ Af,
                                             const short* __restrict__ Avf,
                                             const short* __restrict__ Bf,
                                             const float* __restrict__ lb,
                                             short* __restrict__ hg) {
  __shared__ float ssq[8][TRU];
  __shared__ __align__(16) float Ct[TRU][260];
  const int t = threadIdx.x;
  const int rb = blockIdx.x * TRU;
  const int wid = t >> 6;          // 0..7
  const int lane = t & 63;
  const int wc = wid * 32;         // wave col offset (8 waves cover 256 cols)
  const int m16 = lane & 15;
  const int kg = lane >> 4;        // 0..3
  const int r16b = rb >> 4;

  floatx4 acc[2][2];
  #pragma unroll
  for (int ct = 0; ct < 2; ct++) {
    float b = lb[wc + ct * 16 + m16];
    #pragma unroll
    for (int rt = 0; rt < 2; rt++) acc[rt][ct] = (floatx4){b, b, b, b};
  }

  for (int half = 0; half < 2; ++half) {
    const short* Ab = half ? Avf : (const short*)Af;
    #pragma unroll 2
    for (int kcl = 0; kcl < 8; ++kcl) {
      const int kc = half * 8 + kcl;
      short8 ah[2], al_[2];
      #pragma unroll
      for (int rt = 0; rt < 2; rt++) {
        const short* ap = Ab + ((size_t)((r16b + rt) * 8 + kcl) * 2) * 512 + lane * 8;
        ah[rt]  = *(const short8*)ap;
        al_[rt] = *(const short8*)(ap + 512);
      }
      #pragma unroll
      for (int ct = 0; ct < 2; ct++) {
        const short* bp = Bf + ((size_t)(kc * 16 + wid * 2 + ct) * 2) * 512 + lane * 8;
        short8 bh = *(const short8*)bp;
        short8 bl = *(const short8*)(bp + 512);
        #pragma unroll
        for (int rt = 0; rt < 2; rt++) {
          acc[rt][ct] = __builtin_amdgcn_mfma_f32_16x16x32_bf16(ah[rt], bh, acc[rt][ct], 0, 0, 0);
          acc[rt][ct] = __builtin_amdgcn_mfma_f32_16x16x32_bf16(ah[rt], bl, acc[rt][ct], 0, 0, 0);
          acc[rt][ct] = __builtin_amdgcn_mfma_f32_16x16x32_bf16(al_[rt], bh, acc[rt][ct], 0, 0, 0);
        }
      }
    }
  }

  // ---- epilogue: relu + row l2norm (C/D: col=lane&15, row=(lane>>4)*4+reg)
  float p[2][4];
  #pragma unroll
  for (int rt = 0; rt < 2; rt++)
    #pragma unroll
    for (int reg = 0; reg < 4; reg++) {
      float s = 0.f;
      #pragma unroll
      for (int ct = 0; ct < 2; ct++) {
        float x = fmaxf(acc[rt][ct][reg], 0.f);
        s = fmaf(x, x, s);
      }
      p[rt][reg] = s;
    }
  #pragma unroll
  for (int o = 1; o < 16; o <<= 1)
    #pragma unroll
    for (int rt = 0; rt < 2; rt++)
      #pragma unroll
      for (int reg = 0; reg < 4; reg++)
        p[rt][reg] += __shfl_xor(p[rt][reg], o, 64);
  if (m16 == 0) {
    #pragma unroll
    for (int rt = 0; rt < 2; rt++)
      #pragma unroll
      for (int reg = 0; reg < 4; reg++)
        ssq[wid][rt * 16 + kg * 4 + reg] = p[rt][reg];
  }
  __syncthreads();
  #pragma unroll
  for (int rt = 0; rt < 2; rt++) {
    #pragma unroll
    for (int reg = 0; reg < 4; reg++) {
      int row = rt * 16 + kg * 4 + reg;
      float ss = 0.f;
      #pragma unroll
      for (int ww = 0; ww < 8; ww++) ss += ssq[ww][row];
      float inv = 1.f / fmaxf(sqrtf(ss), 1e-12f);
      #pragma unroll
      for (int ct = 0; ct < 2; ct++) {
        int col = wc + ct * 16 + m16;
        Ct[row][col] = fmaxf(acc[rt][ct][reg], 0.f) * inv;
      }
    }
  }
  __syncthreads();
  // ---- fragment-order split write-back (in-place Af) + bf16 hg, 16B stores
  const int fl = lane;                 // lane-in-fragment
  const int fk = wid;                  // kc 0..7
  #pragma unroll
  for (int r16o = 0; r16o < 2; ++r16o) {
    int row = r16o * 16 + (fl & 15);
    int k0 = fk * 32 + (fl >> 4) * 8;
    float4 xa = *(const float4*)&Ct[row][k0];
    float4 xb = *(const float4*)&Ct[row][k0 + 4];
    short8 H, L;
    H[0] = f2bf(xa.x); H[1] = f2bf(xa.y); H[2] = f2bf(xa.z); H[3] = f2bf(xa.w);
    H[4] = f2bf(xb.x); H[5] = f2bf(xb.y); H[6] = f2bf(xb.z); H[7] = f2bf(xb.w);
    L[0] = f2bf(xa.x - bf2f(H[0])); L[1] = f2bf(xa.y - bf2f(H[1]));
    L[2] = f2bf(xa.z - bf2f(H[2])); L[3] = f2bf(xa.w - bf2f(H[3]));
    L[4] = f2bf(xb.x - bf2f(H[4])); L[5] = f2bf(xb.y - bf2f(H[5]));
    L[6] = f2bf(xb.z - bf2f(H[6])); L[7] = f2bf(xb.w - bf2f(H[7]));
    size_t u = ((size_t)((r16b + r16o) * 8 + fk) * 2) * 512 + (size_t)fl * 8;
    *(short8*)(Af + u) = H;
    *(short8*)(Af + u + 512) = L;
    *(short8*)(hg + (size_t)(rb + row) * DD + k0) = H;
  }
}

// ---------------------------------------------------------------- decode (reads bf16 hg)
__global__ __launch_bounds__(256) void kDec(const short* __restrict__ hg,
                                            const int* __restrict__ aidx,
                                            const float* __restrict__ W4,
                                            const float* __restrict__ W5,
                                            float* __restrict__ Q) {
  __shared__ float tmp[4];
  int b = blockIdx.x, j = threadIdx.x;
  float s = blockSum256(bf2f(hg[(size_t)(NN + b) * DD + j]) * W4[j], tmp);
  int a = aidx[b];
  float za = bf2f(hg[(size_t)a * DD + j]);
  float q = blockSum256(fmaxf(za * s, 0.f) * W5[j], tmp);
  if (j == 0) Q[b] = q;
}

// ---------------------------------------------------------------- launcher
extern "C" void kernel_launch(void* const* d_in, const int* in_sizes, int n_in,
                              void* d_out, int out_size, void* d_ws, size_t ws_size,
                              hipStream_t stream) {
  (void)in_sizes; (void)n_in; (void)out_size; (void)ws_size;
  const int*   edge_src = (const int*)d_in[0];
  const int*   edge_dst = (const int*)d_in[1];
  const float* edge_w   = (const float*)d_in[2];
  const int*   bassign  = (const int*)d_in[3];
  const int*   aidx     = (const int*)d_in[4];
  const float* Xf       = (const float*)d_in[5];
  const float* Xs       = (const float*)d_in[6];
  const float* W1       = (const float*)d_in[7];
  const float* W2       = (const float*)d_in[8];
  const float* W3       = (const float*)d_in[9];
  const float* linW     = (const float*)d_in[10];
  const float* linB     = (const float*)d_in[11];
  const float* W4       = (const float*)d_in[12];
  const float* W5       = (const float*)d_in[13];
  float* Q = (float*)d_out;

  char* base = (char*)d_ws;
  const size_t NB = (size_t)NT * DD * 4;   // 20.5 MB (split-fragment plane-pair bytes)
  short* hg   = (short*)(base);            // NB/2: bf16 h, in-place across depths
  short* Af   = (short*)(base + NB / 2);   // NB: split A-fragments, in-place
  short* Avf  = (short*)(base + NB / 2 + NB);  // NB: split hnv-fragments
  size_t o = NB / 2 + 2 * NB;
  short* Bf   = (short*)(base + o); o += (size_t)DD * 512 * 2 * 2;  // 512 KB, fragment order
  long long* sedge = (long long*)(base + o); o += (size_t)EE * 8;
  int*   snode= (int*)(base + o);   o += (size_t)NN * 4;
  int*   rank = (int*)(base + o);   o += (size_t)EE * 4;
  int*   rankB= (int*)(base + o);   o += (size_t)NN * 4;
  int*   offn = (int*)(base + o);   o += (size_t)(NN + 4) * 4;
  int*   offb = (int*)(base + o);   o += (size_t)(BB + 4) * 4;
  int*   curn = (int*)(base + o);   o += (size_t)NN * 4;
  int*   curb = (int*)(base + o);   o += (size_t)BB * 4;   // contiguous with curn

  hipMemsetAsync(curn, 0, (size_t)(NN + BB) * 4, stream);

  kPre<<<NCB + 512 + NT / 16, 256, 0, stream>>>(Xf, Xs, W1, hg, Af,
                                                edge_dst, bassign, curn, curb,
                                                rank, rankB,
                                                W2, W3, linW, Bf);
  kScan<<<1, 1024, 0, stream>>>(curn, offn, curb, offb);
  kPlace<<<(EE + 255) / 256, 256, 0, stream>>>(edge_src, edge_dst, edge_w, bassign,
                                               offn, offb, rank, rankB, sedge, snode);
  for (int d = 0; d < DEPTH; d++) {
    kAgg<<<4 * (NT / 8), 512, 0, stream>>>(hg, offn, sedge, offb, snode, Avf);
    kUpdM<<<NT / TRU, 512, 0, stream>>>(Af, Avf, Bf, linB, hg);
  }
  kDec<<<BB, 256, 0, stream>>>(hg, aidx, W4, W5, Q);
}